// Round 3
// baseline (1835.120 us; speedup 1.0000x reference)
//
#include <hip/hip_runtime.h>
#include <hip/hip_bf16.h>
#include <math.h>

// ---------------------------------------------------------------------------
// AdvancedTransactionGNN: 3-layer GAT on MI355X.
// GEMM (h=x@W) -> alpha dots -> CSR segment softmax + aggregation per layer.
// Activation storage precision (fp32 vs bf16) chosen at runtime from ws_size:
//   fp32 path needs ~415 MB, bf16 path ~210 MB. All arithmetic is fp32.
// All data-dependent indices are clamped: no device OOB possible.
// ---------------------------------------------------------------------------

// ---------------- storage conversion helpers ----------------

__device__ inline float bf2f(unsigned short u) {
    return __uint_as_float(((unsigned int)u) << 16);
}
__device__ inline unsigned short f2bf(float f) {   // round-nearest-even
    unsigned int x = __float_as_uint(f);
    return (unsigned short)((x + 0x7FFFu + ((x >> 16) & 1u)) >> 16);
}

template <typename T> __device__ inline float  ldf(const T* p);
template <> __device__ inline float ldf<float>(const float* p) { return *p; }
template <> __device__ inline float ldf<unsigned short>(const unsigned short* p) { return bf2f(*p); }

template <typename T> __device__ inline float2 ld2f(const T* p);
template <> __device__ inline float2 ld2f<float>(const float* p) { return *(const float2*)p; }
template <> __device__ inline float2 ld2f<unsigned short>(const unsigned short* p) {
    short2 v = *(const short2*)p;
    return make_float2(bf2f((unsigned short)v.x), bf2f((unsigned short)v.y));
}

template <typename T> __device__ inline float4 ld4f(const T* p);
template <> __device__ inline float4 ld4f<float>(const float* p) { return *(const float4*)p; }
template <> __device__ inline float4 ld4f<unsigned short>(const unsigned short* p) {
    short4 v = *(const short4*)p;
    return make_float4(bf2f((unsigned short)v.x), bf2f((unsigned short)v.y),
                       bf2f((unsigned short)v.z), bf2f((unsigned short)v.w));
}

template <typename T> __device__ inline void stf(T* p, float v);
template <> __device__ inline void stf<float>(float* p, float v) { *p = v; }
template <> __device__ inline void stf<unsigned short>(unsigned short* p, float v) { *p = f2bf(v); }

template <typename T> __device__ inline void st4f(T* p, float4 v);
template <> __device__ inline void st4f<float>(float* p, float4 v) { *(float4*)p = v; }
template <> __device__ inline void st4f<unsigned short>(unsigned short* p, float4 v) {
    short4 s;
    s.x = (short)f2bf(v.x); s.y = (short)f2bf(v.y);
    s.z = (short)f2bf(v.z); s.w = (short)f2bf(v.w);
    *(short4*)p = s;
}

// ---------------- CSR build ----------------

__global__ void count_kernel(const int* __restrict__ ei, int* __restrict__ deg, int E, int N) {
    int i = blockIdx.x * blockDim.x + threadIdx.x;
    if (i < E) {
        int dst = ei[E + i];
        if ((unsigned)dst < (unsigned)N) atomicAdd(&deg[dst], 1);
    }
}

// Single-block inclusive scan of (deg[i] + 1)  -> offs[i+1], cursor[i] = exclusive
__global__ __launch_bounds__(1024) void scan_kernel(const int* __restrict__ deg,
                                                    int* __restrict__ offs,
                                                    int* __restrict__ cursor, int n) {
    __shared__ int sdata[1024];
    __shared__ int carry_s;
    int tid = threadIdx.x;
    if (tid == 0) carry_s = 0;
    __syncthreads();
    for (int base = 0; base < n; base += 1024) {
        int i = base + tid;
        int v = (i < n) ? (deg[i] + 1) : 0;   // +1: self-loop
        sdata[tid] = v;
        __syncthreads();
        #pragma unroll
        for (int off = 1; off < 1024; off <<= 1) {
            int t = (tid >= off) ? sdata[tid - off] : 0;
            __syncthreads();
            sdata[tid] += t;
            __syncthreads();
        }
        int incl = sdata[tid] + carry_s;
        if (i < n) {
            offs[i + 1] = incl;
            cursor[i] = incl - v;
        }
        __syncthreads();
        if (tid == 1023) carry_s = incl;
        __syncthreads();
    }
    if (tid == 0) offs[0] = 0;
}

__global__ void fill_kernel(const int* __restrict__ ei, int* __restrict__ cursor,
                            int* __restrict__ col, int E, int N) {
    int i = blockIdx.x * blockDim.x + threadIdx.x;
    int cap = E + N;
    if (i < E) {
        int src = ei[i];
        int dst = ei[E + i];
        if ((unsigned)src < (unsigned)N && (unsigned)dst < (unsigned)N) {
            int pos = atomicAdd(&cursor[dst], 1);
            if ((unsigned)pos < (unsigned)cap) col[pos] = src;
        }
    } else if (i < cap) {
        int n = i - E;                      // self-loop n -> n
        int pos = atomicAdd(&cursor[n], 1);
        if ((unsigned)pos < (unsigned)cap) col[pos] = n;
    }
}

// ---------------- GEMM: C[M,NOUT] = A[M,K_] @ B[K_,NOUT], fp32 math ----------
// BM=128, BN=64, BK=16, 256 threads, 8x4 register tile. A/C storage templated.

template <int K_, int NOUT, typename TA, typename TC>
__global__ __launch_bounds__(256) void gemm_kernel(const TA* __restrict__ A,
                                                   const float* __restrict__ B,
                                                   TC* __restrict__ C, int M) {
    constexpr int BM = 128, BN = 64, BK = 16;
    __shared__ float As[BK][BM + 4];
    __shared__ float Bs[BK][BN];

    int tid = threadIdx.x;
    int tx = tid % 16;            // output col group (4 cols)
    int ty = tid / 16;            // output row group (8 rows)
    int row0 = blockIdx.x * BM;
    int col0 = blockIdx.y * BN;

    int ar0 = tid / 4;            // 0..63
    int ak  = (tid % 4) * 4;      // 0,4,8,12
    int bk  = tid / 16;           // 0..15
    int bn  = (tid % 16) * 4;     // 0..60

    float acc[8][4];
    #pragma unroll
    for (int i = 0; i < 8; ++i)
        #pragma unroll
        for (int j = 0; j < 4; ++j) acc[i][j] = 0.f;

    for (int k0 = 0; k0 < K_; k0 += BK) {
        #pragma unroll
        for (int i = 0; i < 2; ++i) {
            int r = row0 + ar0 + i * 64;
            float4 v = make_float4(0.f, 0.f, 0.f, 0.f);
            if (r < M) v = ld4f(A + (size_t)r * K_ + k0 + ak);
            As[ak + 0][ar0 + i * 64] = v.x;
            As[ak + 1][ar0 + i * 64] = v.y;
            As[ak + 2][ar0 + i * 64] = v.z;
            As[ak + 3][ar0 + i * 64] = v.w;
        }
        float4 w = *(const float4*)(B + (size_t)(k0 + bk) * NOUT + col0 + bn);
        *(float4*)&Bs[bk][bn] = w;
        __syncthreads();

        #pragma unroll
        for (int k = 0; k < BK; ++k) {
            float4 a0 = *(const float4*)&As[k][ty * 8];
            float4 a1 = *(const float4*)&As[k][ty * 8 + 4];
            float4 b0 = *(const float4*)&Bs[k][tx * 4];
            float a[8] = {a0.x, a0.y, a0.z, a0.w, a1.x, a1.y, a1.z, a1.w};
            float b[4] = {b0.x, b0.y, b0.z, b0.w};
            #pragma unroll
            for (int i = 0; i < 8; ++i)
                #pragma unroll
                for (int j = 0; j < 4; ++j) acc[i][j] = fmaf(a[i], b[j], acc[i][j]);
        }
        __syncthreads();
    }

    #pragma unroll
    for (int i = 0; i < 8; ++i) {
        int r = row0 + ty * 8 + i;
        if (r < M) {
            float4 o = make_float4(acc[i][0], acc[i][1], acc[i][2], acc[i][3]);
            st4f(C + (size_t)r * NOUT + col0 + tx * 4, o);
        }
    }
}

// ---------------- alpha dots: as[n,h] = <h[n,h,:], a_src[h,:]> ----------------

template <int H, int D, typename T>
__global__ __launch_bounds__(256) void alpha_kernel(const T* __restrict__ h,
                                                    const float* __restrict__ a_src,
                                                    const float* __restrict__ a_dst,
                                                    float* __restrict__ as_,
                                                    float* __restrict__ ad_, int N) {
    int wid = blockIdx.x * 4 + threadIdx.x / 64;   // one wave per (n, head)
    int lane = threadIdx.x % 64;
    if (wid >= N * H) return;
    int n = wid / H, hh = wid % H;
    const T* hrow = h + (size_t)n * (H * D) + hh * D;
    float s1 = 0.f, s2 = 0.f;
    #pragma unroll
    for (int d = lane; d < D; d += 64) {
        float v = ldf(hrow + d);
        s1 = fmaf(v, a_src[hh * D + d], s1);
        s2 = fmaf(v, a_dst[hh * D + d], s2);
    }
    #pragma unroll
    for (int off = 32; off > 0; off >>= 1) {
        s1 += __shfl_down(s1, off);
        s2 += __shfl_down(s2, off);
    }
    if (lane == 0) {
        as_[n * H + hh] = s1;
        ad_[n * H + hh] = s2;
    }
}

// ---------------- GAT segment softmax + aggregation (block per dst node) -----

template <int H, int D, int BLOCK, bool DO_ELU, typename TIN, typename TOUT>
__global__ __launch_bounds__(BLOCK) void agg_kernel(const TIN* __restrict__ h,
                                                    const float* __restrict__ asb,
                                                    const float* __restrict__ adb,
                                                    const int* __restrict__ offs,
                                                    const int* __restrict__ col,
                                                    const float* __restrict__ bias,
                                                    TOUT* __restrict__ out, int N) {
    constexpr int C = H * D;
    constexpr int V = C / BLOCK;       // floats per thread
    int node = blockIdx.x;
    int t = threadIdx.x;
    int c0 = t * V;
    int hh = c0 / D;
    int start = offs[node], end = offs[node + 1];
    float adn = adb[node * H + hh];

    // pass 1: per-head running max over incoming edges
    float m = -1e30f;
    for (int j = start; j < end; ++j) {
        int s = col[j];
        if ((unsigned)s >= (unsigned)N) continue;
        float e = asb[s * H + hh] + adn;
        e = (e > 0.f) ? e : 0.2f * e;
        m = fmaxf(m, e);
    }

    // pass 2: exp-sum + weighted accumulation (unnormalized)
    float ssum = 0.f;
    float acc[V];
    #pragma unroll
    for (int v = 0; v < V; ++v) acc[v] = 0.f;

    for (int j = start; j < end; ++j) {
        int s = col[j];
        if ((unsigned)s >= (unsigned)N) continue;
        float e = asb[s * H + hh] + adn;
        e = (e > 0.f) ? e : 0.2f * e;
        float p = __expf(e - m);
        ssum += p;
        const TIN* hrow = h + (size_t)s * C + c0;
        if constexpr (V == 4) {
            float4 hv = ld4f(hrow);
            acc[0] = fmaf(p, hv.x, acc[0]);
            acc[1] = fmaf(p, hv.y, acc[1]);
            acc[2] = fmaf(p, hv.z, acc[2]);
            acc[3] = fmaf(p, hv.w, acc[3]);
        } else if constexpr (V == 2) {
            float2 hv = ld2f(hrow);
            acc[0] = fmaf(p, hv.x, acc[0]);
            acc[1] = fmaf(p, hv.y, acc[1]);
        } else {
            acc[0] = fmaf(p, ldf(hrow), acc[0]);
        }
    }

    float inv = 1.f / (ssum + 1e-16f);
    #pragma unroll
    for (int v = 0; v < V; ++v) {
        float o = acc[v] * inv + bias[c0 + v];
        if (DO_ELU) o = (o > 0.f) ? o : expm1f(o);
        stf(out + (size_t)node * C + c0 + v, o);
    }
}

// ---------------------------------------------------------------------------

extern "C" void kernel_launch(void* const* d_in, const int* in_sizes, int n_in,
                              void* d_out, int out_size, void* d_ws, size_t ws_size,
                              hipStream_t stream) {
    const float* x   = (const float*)d_in[0];
    const int*   ei  = (const int*)d_in[1];   // int32 [2,E]
    const float* W1  = (const float*)d_in[2];
    const float* as1 = (const float*)d_in[3];
    const float* ad1 = (const float*)d_in[4];
    const float* b1  = (const float*)d_in[5];
    const float* W2  = (const float*)d_in[6];
    const float* as2 = (const float*)d_in[7];
    const float* ad2 = (const float*)d_in[8];
    const float* b2  = (const float*)d_in[9];
    const float* W3  = (const float*)d_in[10];
    const float* as3 = (const float*)d_in[11];
    const float* ad3 = (const float*)d_in[12];
    const float* b3  = (const float*)d_in[13];
    float*       out = (float*)d_out;

    const int N = in_sizes[0] / 256;     // 50000
    const int E = in_sizes[1] / 2;       // 400000

    // workspace layout: small arrays first, then two big activation buffers
    size_t off = 0;
    auto alloc = [&](size_t bytes) -> void* {
        void* p = (char*)d_ws + off;
        off += (bytes + 255) & ~(size_t)255;
        return p;
    };
    float* asb    = (float*)alloc((size_t)N * 8 * 4);
    float* adb    = (float*)alloc((size_t)N * 8 * 4);
    int*   deg    = (int*)alloc((size_t)N * 4);
    int*   offs   = (int*)alloc((size_t)(N + 1) * 4);
    int*   cursor = (int*)alloc((size_t)N * 4);
    int*   col    = (int*)alloc((size_t)(E + N) * 4);

    const size_t NB = (size_t)N * 1024;          // elems per big buffer
    const bool f32path = (ws_size >= off + 2 * NB * 4 + (1u << 20));

    // ---- CSR build (shared by both paths) ----
    hipMemsetAsync(deg, 0, (size_t)N * 4, stream);
    count_kernel<<<(E + 255) / 256, 256, 0, stream>>>(ei, deg, E, N);
    scan_kernel<<<1, 1024, 0, stream>>>(deg, offs, cursor, N);
    fill_kernel<<<(E + N + 255) / 256, 256, 0, stream>>>(ei, cursor, col, E, N);

    const int MB = (N + 127) / 128;

    if (f32path) {
        float* B1 = (float*)alloc(NB * 4);
        float* B2 = (float*)alloc(NB * 4);
        // layer 1: 256 -> 8 x 128
        gemm_kernel<256, 1024, float, float><<<dim3(MB, 16), 256, 0, stream>>>(x, W1, B1, N);
        alpha_kernel<8, 128, float><<<(N * 8 + 3) / 4, 256, 0, stream>>>(B1, as1, ad1, asb, adb, N);
        agg_kernel<8, 128, 256, true, float, float><<<N, 256, 0, stream>>>(B1, asb, adb, offs, col, b1, B2, N);
        // layer 2: 1024 -> 4 x 128
        gemm_kernel<1024, 512, float, float><<<dim3(MB, 8), 256, 0, stream>>>(B2, W2, B1, N);
        alpha_kernel<4, 128, float><<<(N * 4 + 3) / 4, 256, 0, stream>>>(B1, as2, ad2, asb, adb, N);
        agg_kernel<4, 128, 256, true, float, float><<<N, 256, 0, stream>>>(B1, asb, adb, offs, col, b2, B2, N);
        // layer 3: 512 -> 1 x 64
        gemm_kernel<512, 64, float, float><<<dim3(MB, 1), 256, 0, stream>>>(B2, W3, B1, N);
        alpha_kernel<1, 64, float><<<(N + 3) / 4, 256, 0, stream>>>(B1, as3, ad3, asb, adb, N);
        agg_kernel<1, 64, 64, false, float, float><<<N, 64, 0, stream>>>(B1, asb, adb, offs, col, b3, out, N);
    } else {
        typedef unsigned short bf;
        bf* B1 = (bf*)alloc(NB * 2);
        bf* B2 = (bf*)alloc(NB * 2);
        // layer 1: 256 -> 8 x 128   (A=x is fp32 input)
        gemm_kernel<256, 1024, float, bf><<<dim3(MB, 16), 256, 0, stream>>>(x, W1, B1, N);
        alpha_kernel<8, 128, bf><<<(N * 8 + 3) / 4, 256, 0, stream>>>(B1, as1, ad1, asb, adb, N);
        agg_kernel<8, 128, 256, true, bf, bf><<<N, 256, 0, stream>>>(B1, asb, adb, offs, col, b1, B2, N);
        // layer 2: 1024 -> 4 x 128
        gemm_kernel<1024, 512, bf, bf><<<dim3(MB, 8), 256, 0, stream>>>(B2, W2, B1, N);
        alpha_kernel<4, 128, bf><<<(N * 4 + 3) / 4, 256, 0, stream>>>(B1, as2, ad2, asb, adb, N);
        agg_kernel<4, 128, 256, true, bf, bf><<<N, 256, 0, stream>>>(B1, asb, adb, offs, col, b2, B2, N);
        // layer 3: 512 -> 1 x 64
        gemm_kernel<512, 64, bf, bf><<<dim3(MB, 1), 256, 0, stream>>>(B2, W3, B1, N);
        alpha_kernel<1, 64, bf><<<(N + 3) / 4, 256, 0, stream>>>(B1, as3, ad3, asb, adb, N);
        agg_kernel<1, 64, 64, false, bf, float><<<N, 64, 0, stream>>>(B1, asb, adb, offs, col, b3, out, N);
    }
}

// Round 4
// 1093.999 us; speedup vs baseline: 1.6774x; 1.6774x over previous
//
#include <hip/hip_runtime.h>
#include <hip/hip_bf16.h>
#include <math.h>

// ---------------------------------------------------------------------------
// AdvancedTransactionGNN: 3-layer GAT on MI355X.
// Layers 1-2 GEMM: bf16 MFMA (16x16x32), 128x128x64 tiles, 4 waves.
// Layer 3 GEMM: fp32 vector (tiny; keeps final map accurate).
// Aggregation: CSR segment softmax, block per node, fp32 math, bf16 storage.
// ---------------------------------------------------------------------------

typedef __attribute__((ext_vector_type(8))) short bf16x8;   // 8 bf16 = 4 VGPR
typedef __attribute__((ext_vector_type(4))) float f32x4;

// ---------------- storage conversion helpers ----------------

__device__ inline float bf2f(unsigned short u) {
    return __uint_as_float(((unsigned int)u) << 16);
}
__device__ inline unsigned short f2bf(float f) {   // round-nearest-even
    unsigned int x = __float_as_uint(f);
    return (unsigned short)((x + 0x7FFFu + ((x >> 16) & 1u)) >> 16);
}

template <typename T> __device__ inline float  ldf(const T* p);
template <> __device__ inline float ldf<float>(const float* p) { return *p; }
template <> __device__ inline float ldf<unsigned short>(const unsigned short* p) { return bf2f(*p); }

template <typename T> __device__ inline float4 ld4f(const T* p);
template <> __device__ inline float4 ld4f<float>(const float* p) { return *(const float4*)p; }
template <> __device__ inline float4 ld4f<unsigned short>(const unsigned short* p) {
    short4 v = *(const short4*)p;
    return make_float4(bf2f((unsigned short)v.x), bf2f((unsigned short)v.y),
                       bf2f((unsigned short)v.z), bf2f((unsigned short)v.w));
}

template <typename T> __device__ inline void stf(T* p, float v);
template <> __device__ inline void stf<float>(float* p, float v) { *p = v; }
template <> __device__ inline void stf<unsigned short>(unsigned short* p, float v) { *p = f2bf(v); }

// ---------------- prep: fp32 -> bf16 convert / weight transpose -------------

__global__ void cvt_bf_kernel(const float* __restrict__ in, unsigned short* __restrict__ out, int n4) {
    int i = blockIdx.x * blockDim.x + threadIdx.x;
    if (i < n4) {
        float4 v = ((const float4*)in)[i];
        short4 s;
        s.x = (short)f2bf(v.x); s.y = (short)f2bf(v.y);
        s.z = (short)f2bf(v.z); s.w = (short)f2bf(v.w);
        ((short4*)out)[i] = s;
    }
}

// Wt[n][k] = bf16(W[k][n]); K, NOUT multiples of 16.
__global__ void transpose_bf_kernel(const float* __restrict__ W, unsigned short* __restrict__ Wt,
                                    int K, int NOUT) {
    __shared__ float tile[16][17];
    int kb = blockIdx.y * 16, nb = blockIdx.x * 16;
    int tx = threadIdx.x, ty = threadIdx.y;
    tile[ty][tx] = W[(size_t)(kb + ty) * NOUT + nb + tx];
    __syncthreads();
    Wt[(size_t)(nb + ty) * K + kb + tx] = f2bf(tile[tx][ty]);
}

// ---------------- CSR build ----------------

__global__ void count_kernel(const int* __restrict__ ei, int* __restrict__ deg, int E, int N) {
    int i = blockIdx.x * blockDim.x + threadIdx.x;
    if (i < E) {
        int dst = ei[E + i];
        if ((unsigned)dst < (unsigned)N) atomicAdd(&deg[dst], 1);
    }
}

__global__ __launch_bounds__(1024) void scan_kernel(const int* __restrict__ deg,
                                                    int* __restrict__ offs,
                                                    int* __restrict__ cursor, int n) {
    __shared__ int sdata[1024];
    __shared__ int carry_s;
    int tid = threadIdx.x;
    if (tid == 0) carry_s = 0;
    __syncthreads();
    for (int base = 0; base < n; base += 1024) {
        int i = base + tid;
        int v = (i < n) ? (deg[i] + 1) : 0;   // +1: self-loop
        sdata[tid] = v;
        __syncthreads();
        #pragma unroll
        for (int off = 1; off < 1024; off <<= 1) {
            int t = (tid >= off) ? sdata[tid - off] : 0;
            __syncthreads();
            sdata[tid] += t;
            __syncthreads();
        }
        int incl = sdata[tid] + carry_s;
        if (i < n) {
            offs[i + 1] = incl;
            cursor[i] = incl - v;
        }
        __syncthreads();
        if (tid == 1023) carry_s = incl;
        __syncthreads();
    }
    if (tid == 0) offs[0] = 0;
}

__global__ void fill_kernel(const int* __restrict__ ei, int* __restrict__ cursor,
                            int* __restrict__ col, int E, int N) {
    int i = blockIdx.x * blockDim.x + threadIdx.x;
    int cap = E + N;
    if (i < E) {
        int src = ei[i];
        int dst = ei[E + i];
        if ((unsigned)src < (unsigned)N && (unsigned)dst < (unsigned)N) {
            int pos = atomicAdd(&cursor[dst], 1);
            if ((unsigned)pos < (unsigned)cap) col[pos] = src;
        }
    } else if (i < cap) {
        int n = i - E;
        int pos = atomicAdd(&cursor[n], 1);
        if ((unsigned)pos < (unsigned)cap) col[pos] = n;
    }
}

// ---------------- bf16 MFMA GEMM: C[M,NOUT] = A[M,K_] @ Bt[NOUT,K_]^T --------
// BM=128, BN=128, BK=64; 256 threads = 4 waves; each wave: 64x64 (4x4 frags).
// LDS rows padded +8 bf16 (stride 144B) to spread b128 reads across banks.

template <int K_, int NOUT, typename TC>
__global__ __launch_bounds__(256) void gemm_mfma(const unsigned short* __restrict__ A,
                                                 const unsigned short* __restrict__ Bt,
                                                 TC* __restrict__ C, int M) {
    constexpr int BM = 128, BN = 128, BK = 64;
    constexpr int LDT = BK + 8;   // 72 bf16 = 144 B row stride
    __shared__ unsigned short Als[BM][LDT];
    __shared__ unsigned short Bls[BN][LDT];

    int tid = threadIdx.x;
    int lane = tid & 63, wave = tid >> 6;
    int wr = (wave >> 1) * 64, wc = (wave & 1) * 64;
    int row0 = blockIdx.x * BM, col0 = blockIdx.y * BN;

    int sr = tid >> 3;            // 0..31: staging row within group of 32
    int sk = (tid & 7) * 8;       // 0..56: bf16 col offset (16B granule)

    f32x4 acc[4][4] = {};

    for (int k0 = 0; k0 < K_; k0 += BK) {
        #pragma unroll
        for (int i = 0; i < 4; ++i) {
            int r = sr + i * 32;
            int gr = row0 + r;
            uint4 va = make_uint4(0u, 0u, 0u, 0u);
            if (gr < M) va = *(const uint4*)(A + (size_t)gr * K_ + k0 + sk);
            *(uint4*)&Als[r][sk] = va;
            uint4 vb = *(const uint4*)(Bt + (size_t)(col0 + r) * K_ + k0 + sk);
            *(uint4*)&Bls[r][sk] = vb;
        }
        __syncthreads();
        #pragma unroll
        for (int kh = 0; kh < 2; ++kh) {
            int kk = kh * 32 + (lane >> 4) * 8;
            bf16x8 a[4], b[4];
            #pragma unroll
            for (int m = 0; m < 4; ++m)
                a[m] = *(const bf16x8*)&Als[wr + m * 16 + (lane & 15)][kk];
            #pragma unroll
            for (int n = 0; n < 4; ++n)
                b[n] = *(const bf16x8*)&Bls[wc + n * 16 + (lane & 15)][kk];
            #pragma unroll
            for (int m = 0; m < 4; ++m)
                #pragma unroll
                for (int n = 0; n < 4; ++n)
                    acc[m][n] = __builtin_amdgcn_mfma_f32_16x16x32_bf16(a[m], b[n], acc[m][n], 0, 0, 0);
        }
        __syncthreads();
    }

    // epilogue: C row = (lane>>4)*4 + reg, col = lane&15  [guide-verified]
    int fr = lane & 15, fq = lane >> 4;
    #pragma unroll
    for (int m = 0; m < 4; ++m) {
        #pragma unroll
        for (int j = 0; j < 4; ++j) {
            int r = row0 + wr + m * 16 + fq * 4 + j;
            if (r < M) {
                #pragma unroll
                for (int n = 0; n < 4; ++n)
                    stf(C + (size_t)r * NOUT + col0 + wc + n * 16 + fr, acc[m][n][j]);
            }
        }
    }
}

// ---------------- fp32 GEMM (layer 3): C = A @ B ----------------

template <int K_, int NOUT, typename TA, typename TC>
__global__ __launch_bounds__(256) void gemm_kernel(const TA* __restrict__ A,
                                                   const float* __restrict__ B,
                                                   TC* __restrict__ C, int M) {
    constexpr int BM = 128, BN = 64, BK = 16;
    __shared__ float As[BK][BM + 4];
    __shared__ float Bs[BK][BN];

    int tid = threadIdx.x;
    int tx = tid % 16;
    int ty = tid / 16;
    int row0 = blockIdx.x * BM;
    int col0 = blockIdx.y * BN;

    int ar0 = tid / 4;
    int ak  = (tid % 4) * 4;
    int bk  = tid / 16;
    int bn  = (tid % 16) * 4;

    float acc[8][4];
    #pragma unroll
    for (int i = 0; i < 8; ++i)
        #pragma unroll
        for (int j = 0; j < 4; ++j) acc[i][j] = 0.f;

    for (int k0 = 0; k0 < K_; k0 += BK) {
        #pragma unroll
        for (int i = 0; i < 2; ++i) {
            int r = row0 + ar0 + i * 64;
            float4 v = make_float4(0.f, 0.f, 0.f, 0.f);
            if (r < M) v = ld4f(A + (size_t)r * K_ + k0 + ak);
            As[ak + 0][ar0 + i * 64] = v.x;
            As[ak + 1][ar0 + i * 64] = v.y;
            As[ak + 2][ar0 + i * 64] = v.z;
            As[ak + 3][ar0 + i * 64] = v.w;
        }
        float4 w = *(const float4*)(B + (size_t)(k0 + bk) * NOUT + col0 + bn);
        *(float4*)&Bs[bk][bn] = w;
        __syncthreads();

        #pragma unroll
        for (int k = 0; k < BK; ++k) {
            float4 a0 = *(const float4*)&As[k][ty * 8];
            float4 a1 = *(const float4*)&As[k][ty * 8 + 4];
            float4 b0 = *(const float4*)&Bs[k][tx * 4];
            float a[8] = {a0.x, a0.y, a0.z, a0.w, a1.x, a1.y, a1.z, a1.w};
            float b[4] = {b0.x, b0.y, b0.z, b0.w};
            #pragma unroll
            for (int i = 0; i < 8; ++i)
                #pragma unroll
                for (int j = 0; j < 4; ++j) acc[i][j] = fmaf(a[i], b[j], acc[i][j]);
        }
        __syncthreads();
    }

    #pragma unroll
    for (int i = 0; i < 8; ++i) {
        int r = row0 + ty * 8 + i;
        if (r < M) {
            #pragma unroll
            for (int j = 0; j < 4; ++j)
                stf(C + (size_t)r * NOUT + col0 + tx * 4 + j, acc[i][j]);
        }
    }
}

// ---------------- alpha dots: as[n,h] = <h[n,h,:], a_src[h,:]> ----------------

template <int H, int D, typename T>
__global__ __launch_bounds__(256) void alpha_kernel(const T* __restrict__ h,
                                                    const float* __restrict__ a_src,
                                                    const float* __restrict__ a_dst,
                                                    float* __restrict__ as_,
                                                    float* __restrict__ ad_, int N) {
    int wid = blockIdx.x * 4 + threadIdx.x / 64;
    int lane = threadIdx.x % 64;
    if (wid >= N * H) return;
    int n = wid / H, hh = wid % H;
    const T* hrow = h + (size_t)n * (H * D) + hh * D;
    float s1 = 0.f, s2 = 0.f;
    #pragma unroll
    for (int d = lane; d < D; d += 64) {
        float v = ldf(hrow + d);
        s1 = fmaf(v, a_src[hh * D + d], s1);
        s2 = fmaf(v, a_dst[hh * D + d], s2);
    }
    #pragma unroll
    for (int off = 32; off > 0; off >>= 1) {
        s1 += __shfl_down(s1, off);
        s2 += __shfl_down(s2, off);
    }
    if (lane == 0) {
        as_[n * H + hh] = s1;
        ad_[n * H + hh] = s2;
    }
}

// ---------------- GAT segment softmax + aggregation (block per dst node) -----

template <int H, int D, int BLOCK, bool DO_ELU, typename TIN, typename TOUT>
__global__ __launch_bounds__(BLOCK) void agg_kernel(const TIN* __restrict__ h,
                                                    const float* __restrict__ asb,
                                                    const float* __restrict__ adb,
                                                    const int* __restrict__ offs,
                                                    const int* __restrict__ col,
                                                    const float* __restrict__ bias,
                                                    TOUT* __restrict__ out, int N) {
    constexpr int C = H * D;
    constexpr int V = C / BLOCK;
    int node = blockIdx.x;
    int t = threadIdx.x;
    int c0 = t * V;
    int hh = c0 / D;
    int start = offs[node], end = offs[node + 1];
    float adn = adb[node * H + hh];

    float m = -1e30f;
    for (int j = start; j < end; ++j) {
        int s = col[j];
        if ((unsigned)s >= (unsigned)N) continue;
        float e = asb[s * H + hh] + adn;
        e = (e > 0.f) ? e : 0.2f * e;
        m = fmaxf(m, e);
    }

    float ssum = 0.f;
    float acc[V];
    #pragma unroll
    for (int v = 0; v < V; ++v) acc[v] = 0.f;

    for (int j = start; j < end; ++j) {
        int s = col[j];
        if ((unsigned)s >= (unsigned)N) continue;
        float e = asb[s * H + hh] + adn;
        e = (e > 0.f) ? e : 0.2f * e;
        float p = __expf(e - m);
        ssum += p;
        const TIN* hrow = h + (size_t)s * C + c0;
        if constexpr (V == 4) {
            float4 hv = ld4f(hrow);
            acc[0] = fmaf(p, hv.x, acc[0]);
            acc[1] = fmaf(p, hv.y, acc[1]);
            acc[2] = fmaf(p, hv.z, acc[2]);
            acc[3] = fmaf(p, hv.w, acc[3]);
        } else {
            #pragma unroll
            for (int v = 0; v < V; ++v) acc[v] = fmaf(p, ldf(hrow + v), acc[v]);
        }
    }

    float inv = 1.f / (ssum + 1e-16f);
    #pragma unroll
    for (int v = 0; v < V; ++v) {
        float o = acc[v] * inv + bias[c0 + v];
        if (DO_ELU) o = (o > 0.f) ? o : expm1f(o);
        stf(out + (size_t)node * C + c0 + v, o);
    }
}

// ---------------------------------------------------------------------------

extern "C" void kernel_launch(void* const* d_in, const int* in_sizes, int n_in,
                              void* d_out, int out_size, void* d_ws, size_t ws_size,
                              hipStream_t stream) {
    const float* x   = (const float*)d_in[0];
    const int*   ei  = (const int*)d_in[1];
    const float* W1  = (const float*)d_in[2];
    const float* as1 = (const float*)d_in[3];
    const float* ad1 = (const float*)d_in[4];
    const float* b1  = (const float*)d_in[5];
    const float* W2  = (const float*)d_in[6];
    const float* as2 = (const float*)d_in[7];
    const float* ad2 = (const float*)d_in[8];
    const float* b2  = (const float*)d_in[9];
    const float* W3  = (const float*)d_in[10];
    const float* as3 = (const float*)d_in[11];
    const float* ad3 = (const float*)d_in[12];
    const float* b3  = (const float*)d_in[13];
    float*       out = (float*)d_out;

    const int N = in_sizes[0] / 256;     // 50000
    const int E = in_sizes[1] / 2;       // 400000

    typedef unsigned short bf;
    size_t off = 0;
    auto alloc = [&](size_t bytes) -> void* {
        void* p = (char*)d_ws + off;
        off += (bytes + 255) & ~(size_t)255;
        return p;
    };
    float* asb    = (float*)alloc((size_t)N * 8 * 4);
    float* adb    = (float*)alloc((size_t)N * 8 * 4);
    int*   deg    = (int*)alloc((size_t)N * 4);
    int*   offs   = (int*)alloc((size_t)(N + 1) * 4);
    int*   cursor = (int*)alloc((size_t)N * 4);
    int*   col    = (int*)alloc((size_t)(E + N) * 4);
    bf*    W1t    = (bf*)alloc((size_t)256 * 1024 * 2);   // [1024][256]
    bf*    W2t    = (bf*)alloc((size_t)1024 * 512 * 2);   // [512][1024]
    const size_t NB = (size_t)N * 1024;
    bf* B1 = (bf*)alloc(NB * 2);
    bf* B2 = (bf*)alloc(NB * 2);
    bf* x_bf = B2;   // x_bf (25.6MB) lives in B2's region; dead before agg1 writes B2

    // ---- CSR build ----
    hipMemsetAsync(deg, 0, (size_t)N * 4, stream);
    count_kernel<<<(E + 255) / 256, 256, 0, stream>>>(ei, deg, E, N);
    scan_kernel<<<1, 1024, 0, stream>>>(deg, offs, cursor, N);
    fill_kernel<<<(E + N + 255) / 256, 256, 0, stream>>>(ei, cursor, col, E, N);

    // ---- prep: x -> bf16, W1/W2 -> transposed bf16 ----
    {
        int n4 = N * 256 / 4;
        cvt_bf_kernel<<<(n4 + 255) / 256, 256, 0, stream>>>(x, x_bf, n4);
        transpose_bf_kernel<<<dim3(1024 / 16, 256 / 16), dim3(16, 16), 0, stream>>>(W1, W1t, 256, 1024);
        transpose_bf_kernel<<<dim3(512 / 16, 1024 / 16), dim3(16, 16), 0, stream>>>(W2, W2t, 1024, 512);
    }

    const int MBm = (N + 127) / 128;

    // ---- layer 1: 256 -> 8 x 128 (MFMA) ----
    gemm_mfma<256, 1024, bf><<<dim3(MBm, 8), 256, 0, stream>>>(x_bf, W1t, B1, N);
    alpha_kernel<8, 128, bf><<<(N * 8 + 3) / 4, 256, 0, stream>>>(B1, as1, ad1, asb, adb, N);
    agg_kernel<8, 128, 256, true, bf, bf><<<N, 256, 0, stream>>>(B1, asb, adb, offs, col, b1, B2, N);

    // ---- layer 2: 1024 -> 4 x 128 (MFMA) ----
    gemm_mfma<1024, 512, bf><<<dim3(MBm, 4), 256, 0, stream>>>(B2, W2t, B1, N);
    alpha_kernel<4, 128, bf><<<(N * 4 + 3) / 4, 256, 0, stream>>>(B1, as2, ad2, asb, adb, N);
    agg_kernel<4, 128, 256, true, bf, bf><<<N, 256, 0, stream>>>(B1, asb, adb, offs, col, b2, B2, N);

    // ---- layer 3: 512 -> 1 x 64 (fp32 vector, accuracy hedge) ----
    gemm_kernel<512, 64, bf, bf><<<dim3(MBm, 1), 256, 0, stream>>>(B2, W3, B1, N);
    alpha_kernel<1, 64, bf><<<(N + 3) / 4, 256, 0, stream>>>(B1, as3, ad3, asb, adb, N);
    agg_kernel<1, 64, 64, false, bf, float><<<N, 64, 0, stream>>>(B1, asb, adb, offs, col, b3, out, N);
}

// Round 7
// 848.580 us; speedup vs baseline: 2.1626x; 1.2892x over previous
//
#include <hip/hip_runtime.h>
#include <hip/hip_bf16.h>
#include <math.h>

// ---------------------------------------------------------------------------
// AdvancedTransactionGNN: 3-layer GAT on MI355X.
// Layers 1-2 GEMM: bf16 MFMA (16x16x32), 128x128x64 tiles, 4 waves.
// Layer 3 GEMM: fp32 vector (tiny; keeps final map accurate).
// Aggregation: CSR segment softmax, block per node, ONLINE single-pass with
// chunked LDS edge staging (breaks the serial col->asb->h latency chain).
// ---------------------------------------------------------------------------

typedef __attribute__((ext_vector_type(8))) short bf16x8;   // 8 bf16 = 4 VGPR
typedef __attribute__((ext_vector_type(4))) float f32x4;
typedef __attribute__((ext_vector_type(2))) unsigned int u32x2;

// ---------------- storage conversion helpers ----------------

__device__ inline float bf2f(unsigned short u) {
    return __uint_as_float(((unsigned int)u) << 16);
}
__device__ inline unsigned short f2bf(float f) {   // round-nearest-even
    unsigned int x = __float_as_uint(f);
    return (unsigned short)((x + 0x7FFFu + ((x >> 16) & 1u)) >> 16);
}
__device__ inline unsigned int pack2bf(float lo, float hi) {
    return (unsigned int)f2bf(lo) | ((unsigned int)f2bf(hi) << 16);
}

template <typename T> __device__ inline float  ldf(const T* p);
template <> __device__ inline float ldf<float>(const float* p) { return *p; }
template <> __device__ inline float ldf<unsigned short>(const unsigned short* p) { return bf2f(*p); }

template <typename T> __device__ inline float4 ld4f(const T* p);
template <> __device__ inline float4 ld4f<float>(const float* p) { return *(const float4*)p; }
template <> __device__ inline float4 ld4f<unsigned short>(const unsigned short* p) {
    short4 v = *(const short4*)p;
    return make_float4(bf2f((unsigned short)v.x), bf2f((unsigned short)v.y),
                       bf2f((unsigned short)v.z), bf2f((unsigned short)v.w));
}

template <typename T> __device__ inline float2 ld2f(const T* p);
template <> __device__ inline float2 ld2f<float>(const float* p) { return *(const float2*)p; }
template <> __device__ inline float2 ld2f<unsigned short>(const unsigned short* p) {
    short2 v = *(const short2*)p;
    return make_float2(bf2f((unsigned short)v.x), bf2f((unsigned short)v.y));
}

template <typename T> __device__ inline void stf(T* p, float v);
template <> __device__ inline void stf<float>(float* p, float v) { *p = v; }
template <> __device__ inline void stf<unsigned short>(unsigned short* p, float v) { *p = f2bf(v); }

// ---------------- prep: fp32 -> bf16 convert / weight transpose -------------

__global__ void cvt_bf_kernel(const float* __restrict__ in, unsigned short* __restrict__ out, int n4) {
    int i = blockIdx.x * blockDim.x + threadIdx.x;
    if (i < n4) {
        float4 v = ((const float4*)in)[i];
        short4 s;
        s.x = (short)f2bf(v.x); s.y = (short)f2bf(v.y);
        s.z = (short)f2bf(v.z); s.w = (short)f2bf(v.w);
        ((short4*)out)[i] = s;
    }
}

// Wt[n][k] = bf16(W[k][n]); K, NOUT multiples of 16.
__global__ void transpose_bf_kernel(const float* __restrict__ W, unsigned short* __restrict__ Wt,
                                    int K, int NOUT) {
    __shared__ float tile[16][17];
    int kb = blockIdx.y * 16, nb = blockIdx.x * 16;
    int tx = threadIdx.x, ty = threadIdx.y;
    tile[ty][tx] = W[(size_t)(kb + ty) * NOUT + nb + tx];
    __syncthreads();
    Wt[(size_t)(nb + ty) * K + kb + tx] = f2bf(tile[tx][ty]);
}

// ---------------- CSR build ----------------

__global__ void count_kernel(const int* __restrict__ ei, int* __restrict__ deg, int E, int N) {
    int i = blockIdx.x * blockDim.x + threadIdx.x;
    if (i < E) {
        int dst = ei[E + i];
        if ((unsigned)dst < (unsigned)N) atomicAdd(&deg[dst], 1);
    }
}

__global__ __launch_bounds__(1024) void scan_kernel(const int* __restrict__ deg,
                                                    int* __restrict__ offs,
                                                    int* __restrict__ cursor, int n) {
    __shared__ int sdata[1024];
    __shared__ int carry_s;
    int tid = threadIdx.x;
    if (tid == 0) carry_s = 0;
    __syncthreads();
    for (int base = 0; base < n; base += 1024) {
        int i = base + tid;
        int v = (i < n) ? (deg[i] + 1) : 0;   // +1: self-loop
        sdata[tid] = v;
        __syncthreads();
        #pragma unroll
        for (int off = 1; off < 1024; off <<= 1) {
            int t = (tid >= off) ? sdata[tid - off] : 0;
            __syncthreads();
            sdata[tid] += t;
            __syncthreads();
        }
        int incl = sdata[tid] + carry_s;
        if (i < n) {
            offs[i + 1] = incl;
            cursor[i] = incl - v;
        }
        __syncthreads();
        if (tid == 1023) carry_s = incl;
        __syncthreads();
    }
    if (tid == 0) offs[0] = 0;
}

__global__ void fill_kernel(const int* __restrict__ ei, int* __restrict__ cursor,
                            int* __restrict__ col, int E, int N) {
    int i = blockIdx.x * blockDim.x + threadIdx.x;
    int cap = E + N;
    if (i < E) {
        int src = ei[i];
        int dst = ei[E + i];
        if ((unsigned)src < (unsigned)N && (unsigned)dst < (unsigned)N) {
            int pos = atomicAdd(&cursor[dst], 1);
            if ((unsigned)pos < (unsigned)cap) col[pos] = src;
        }
    } else if (i < cap) {
        int n = i - E;
        int pos = atomicAdd(&cursor[n], 1);
        if ((unsigned)pos < (unsigned)cap) col[pos] = n;
    }
}

// ---------------- bf16 MFMA GEMM: C[M,NOUT] = A[M,K_] @ Bt[NOUT,K_]^T --------

template <int K_, int NOUT, typename TC>
__global__ __launch_bounds__(256) void gemm_mfma(const unsigned short* __restrict__ A,
                                                 const unsigned short* __restrict__ Bt,
                                                 TC* __restrict__ C, int M) {
    constexpr int BM = 128, BN = 128, BK = 64;
    constexpr int LDT = BK + 8;
    __shared__ unsigned short Als[BM][LDT];
    __shared__ unsigned short Bls[BN][LDT];

    int tid = threadIdx.x;
    int lane = tid & 63, wave = tid >> 6;
    int wr = (wave >> 1) * 64, wc = (wave & 1) * 64;
    int row0 = blockIdx.x * BM, col0 = blockIdx.y * BN;

    int sr = tid >> 3;
    int sk = (tid & 7) * 8;

    f32x4 acc[4][4] = {};

    for (int k0 = 0; k0 < K_; k0 += BK) {
        #pragma unroll
        for (int i = 0; i < 4; ++i) {
            int r = sr + i * 32;
            int gr = row0 + r;
            uint4 va = make_uint4(0u, 0u, 0u, 0u);
            if (gr < M) va = *(const uint4*)(A + (size_t)gr * K_ + k0 + sk);
            *(uint4*)&Als[r][sk] = va;
            uint4 vb = *(const uint4*)(Bt + (size_t)(col0 + r) * K_ + k0 + sk);
            *(uint4*)&Bls[r][sk] = vb;
        }
        __syncthreads();
        #pragma unroll
        for (int kh = 0; kh < 2; ++kh) {
            int kk = kh * 32 + (lane >> 4) * 8;
            bf16x8 a[4], b[4];
            #pragma unroll
            for (int m = 0; m < 4; ++m)
                a[m] = *(const bf16x8*)&Als[wr + m * 16 + (lane & 15)][kk];
            #pragma unroll
            for (int n = 0; n < 4; ++n)
                b[n] = *(const bf16x8*)&Bls[wc + n * 16 + (lane & 15)][kk];
            #pragma unroll
            for (int m = 0; m < 4; ++m)
                #pragma unroll
                for (int n = 0; n < 4; ++n)
                    acc[m][n] = __builtin_amdgcn_mfma_f32_16x16x32_bf16(a[m], b[n], acc[m][n], 0, 0, 0);
        }
        __syncthreads();
    }

    int fr = lane & 15, fq = lane >> 4;
    #pragma unroll
    for (int m = 0; m < 4; ++m) {
        #pragma unroll
        for (int j = 0; j < 4; ++j) {
            int r = row0 + wr + m * 16 + fq * 4 + j;
            if (r < M) {
                #pragma unroll
                for (int n = 0; n < 4; ++n)
                    stf(C + (size_t)r * NOUT + col0 + wc + n * 16 + fr, acc[m][n][j]);
            }
        }
    }
}

// ---------------- fp32 GEMM (layer 3): C = A @ B ----------------

template <int K_, int NOUT, typename TA, typename TC>
__global__ __launch_bounds__(256) void gemm_kernel(const TA* __restrict__ A,
                                                   const float* __restrict__ B,
                                                   TC* __restrict__ C, int M) {
    constexpr int BM = 128, BN = 64, BK = 16;
    __shared__ float As[BK][BM + 4];
    __shared__ float Bs[BK][BN];

    int tid = threadIdx.x;
    int tx = tid % 16;
    int ty = tid / 16;
    int row0 = blockIdx.x * BM;
    int col0 = blockIdx.y * BN;

    int ar0 = tid / 4;
    int ak  = (tid % 4) * 4;
    int bk  = tid / 16;
    int bn  = (tid % 16) * 4;

    float acc[8][4];
    #pragma unroll
    for (int i = 0; i < 8; ++i)
        #pragma unroll
        for (int j = 0; j < 4; ++j) acc[i][j] = 0.f;

    for (int k0 = 0; k0 < K_; k0 += BK) {
        #pragma unroll
        for (int i = 0; i < 2; ++i) {
            int r = row0 + ar0 + i * 64;
            float4 v = make_float4(0.f, 0.f, 0.f, 0.f);
            if (r < M) v = ld4f(A + (size_t)r * K_ + k0 + ak);
            As[ak + 0][ar0 + i * 64] = v.x;
            As[ak + 1][ar0 + i * 64] = v.y;
            As[ak + 2][ar0 + i * 64] = v.z;
            As[ak + 3][ar0 + i * 64] = v.w;
        }
        float4 w = *(const float4*)(B + (size_t)(k0 + bk) * NOUT + col0 + bn);
        *(float4*)&Bs[bk][bn] = w;
        __syncthreads();

        #pragma unroll
        for (int k = 0; k < BK; ++k) {
            float4 a0 = *(const float4*)&As[k][ty * 8];
            float4 a1 = *(const float4*)&As[k][ty * 8 + 4];
            float4 b0 = *(const float4*)&Bs[k][tx * 4];
            float a[8] = {a0.x, a0.y, a0.z, a0.w, a1.x, a1.y, a1.z, a1.w};
            float b[4] = {b0.x, b0.y, b0.z, b0.w};
            #pragma unroll
            for (int i = 0; i < 8; ++i)
                #pragma unroll
                for (int j = 0; j < 4; ++j) acc[i][j] = fmaf(a[i], b[j], acc[i][j]);
        }
        __syncthreads();
    }

    #pragma unroll
    for (int i = 0; i < 8; ++i) {
        int r = row0 + ty * 8 + i;
        if (r < M) {
            #pragma unroll
            for (int j = 0; j < 4; ++j)
                stf(C + (size_t)r * NOUT + col0 + tx * 4 + j, acc[i][j]);
        }
    }
}

// ---------------- alpha dots ----------------
// Fast path for D=128: one wave per node, 16B/lane loads, 16-lane groups own
// one head each; H/4 iterations of 512 contiguous bf16.

template <int H>
__global__ __launch_bounds__(256) void alpha128_kernel(const unsigned short* __restrict__ h,
                                                       const float* __restrict__ a_src,
                                                       const float* __restrict__ a_dst,
                                                       float* __restrict__ asb,
                                                       float* __restrict__ adb, int N) {
    int node = blockIdx.x * 4 + (threadIdx.x >> 6);
    if (node >= N) return;
    int lane = threadIdx.x & 63;
    const unsigned short* row = h + (size_t)node * (H * 128);
    #pragma unroll
    for (int it = 0; it < H / 4; ++it) {
        int head = it * 4 + (lane >> 4);
        int eoff = it * 512 + (lane >> 4) * 128 + (lane & 15) * 8;
        const unsigned short* p = row + eoff;
        float4 v0 = ld4f(p);
        float4 v1 = ld4f(p + 4);
        const float* asp = a_src + head * 128 + (lane & 15) * 8;
        const float* adp = a_dst + head * 128 + (lane & 15) * 8;
        float4 s0 = *(const float4*)asp, s1 = *(const float4*)(asp + 4);
        float4 d0 = *(const float4*)adp, d1 = *(const float4*)(adp + 4);
        float r1 = v0.x * s0.x + v0.y * s0.y + v0.z * s0.z + v0.w * s0.w
                 + v1.x * s1.x + v1.y * s1.y + v1.z * s1.z + v1.w * s1.w;
        float r2 = v0.x * d0.x + v0.y * d0.y + v0.z * d0.z + v0.w * d0.w
                 + v1.x * d1.x + v1.y * d1.y + v1.z * d1.z + v1.w * d1.w;
        #pragma unroll
        for (int off = 1; off < 16; off <<= 1) {
            r1 += __shfl_xor(r1, off);
            r2 += __shfl_xor(r2, off);
        }
        if ((lane & 15) == 0) {
            asb[node * H + head] = r1;
            adb[node * H + head] = r2;
        }
    }
}

// generic (layer 3: H=1, D=64)
template <int H, int D, typename T>
__global__ __launch_bounds__(256) void alpha_kernel(const T* __restrict__ h,
                                                    const float* __restrict__ a_src,
                                                    const float* __restrict__ a_dst,
                                                    float* __restrict__ as_,
                                                    float* __restrict__ ad_, int N) {
    int wid = blockIdx.x * 4 + threadIdx.x / 64;
    int lane = threadIdx.x % 64;
    if (wid >= N * H) return;
    int n = wid / H, hh = wid % H;
    const T* hrow = h + (size_t)n * (H * D) + hh * D;
    float s1 = 0.f, s2 = 0.f;
    #pragma unroll
    for (int d = lane; d < D; d += 64) {
        float v = ldf(hrow + d);
        s1 = fmaf(v, a_src[hh * D + d], s1);
        s2 = fmaf(v, a_dst[hh * D + d], s2);
    }
    #pragma unroll
    for (int off = 32; off > 0; off >>= 1) {
        s1 += __shfl_down(s1, off);
        s2 += __shfl_down(s2, off);
    }
    if (lane == 0) {
        as_[n * H + hh] = s1;
        ad_[n * H + hh] = s2;
    }
}

// ---------------- GAT aggregation: online softmax, chunked LDS staging ------
// Per chunk of CH=BLOCK/H edges: all threads stage e[j][head] + col[j] into
// LDS in one parallel round-trip; accumulate loop then has a single
// independent global load (h row) per edge, 2-way unrolled.

template <int H, int D, int BLOCK, bool DO_ELU, typename TIN, typename TOUT>
__global__ __launch_bounds__(BLOCK) void agg_kernel(const TIN* __restrict__ h,
                                                    const float* __restrict__ asb,
                                                    const float* __restrict__ adb,
                                                    const int* __restrict__ offs,
                                                    const int* __restrict__ col,
                                                    const float* __restrict__ bias,
                                                    TOUT* __restrict__ out, int N) {
    constexpr int C = H * D;
    constexpr int V = C / BLOCK;        // 4 (L1), 2 (L2), 1 (L3)
    constexpr int CH = BLOCK / H;       // 32, 64, 64
    __shared__ float e_s[CH][H];
    __shared__ int   col_s[CH];

    int node = blockIdx.x;
    int t = threadIdx.x;
    int c0 = t * V;
    int hh = c0 / D;
    int start = offs[node], end = offs[node + 1];

    int sj = t / H;                     // stage role: edge slot
    int sh = t % H;                     // stage role: head
    float adn_stage = adb[node * H + sh];

    float m = -1e30f, ssum = 0.f;
    float acc[V];
    #pragma unroll
    for (int v = 0; v < V; ++v) acc[v] = 0.f;

    for (int base = start; base < end; base += CH) {
        int len = min(CH, end - base);
        __syncthreads();                // previous chunk's LDS readers done
        if (sj < len) {
            int s = col[base + sj];
            float e;
            if ((unsigned)s < (unsigned)N) {
                e = asb[s * H + sh] + adn_stage;
                e = (e > 0.f) ? e : 0.2f * e;
            } else { e = -1e30f; s = node; }
            e_s[sj][sh] = e;
            if (sh == 0) col_s[sj] = s;
        }
        __syncthreads();

        // chunk max for my head (LDS broadcast reads)
        float cm = -1e30f;
        for (int j = 0; j < len; ++j) cm = fmaxf(cm, e_s[j][hh]);
        float mn = fmaxf(m, cm);
        float scale = __expf(m - mn);   // first chunk: exp(-inf)=0, acc/ssum are 0
        ssum *= scale;
        #pragma unroll
        for (int v = 0; v < V; ++v) acc[v] *= scale;
        m = mn;

        int j = 0;
        for (; j + 1 < len; j += 2) {
            int s0 = col_s[j], s1 = col_s[j + 1];
            float p0 = __expf(e_s[j][hh] - m);
            float p1 = __expf(e_s[j + 1][hh] - m);
            const TIN* r0 = h + (size_t)s0 * C + c0;
            const TIN* r1 = h + (size_t)s1 * C + c0;
            if constexpr (V == 4) {
                float4 a0 = ld4f(r0), a1 = ld4f(r1);
                acc[0] = fmaf(p0, a0.x, fmaf(p1, a1.x, acc[0]));
                acc[1] = fmaf(p0, a0.y, fmaf(p1, a1.y, acc[1]));
                acc[2] = fmaf(p0, a0.z, fmaf(p1, a1.z, acc[2]));
                acc[3] = fmaf(p0, a0.w, fmaf(p1, a1.w, acc[3]));
            } else if constexpr (V == 2) {
                float2 a0 = ld2f(r0), a1 = ld2f(r1);
                acc[0] = fmaf(p0, a0.x, fmaf(p1, a1.x, acc[0]));
                acc[1] = fmaf(p0, a0.y, fmaf(p1, a1.y, acc[1]));
            } else {
                acc[0] = fmaf(p0, ldf(r0), fmaf(p1, ldf(r1), acc[0]));
            }
            ssum += p0 + p1;
        }
        if (j < len) {
            int s0 = col_s[j];
            float p0 = __expf(e_s[j][hh] - m);
            const TIN* r0 = h + (size_t)s0 * C + c0;
            if constexpr (V == 4) {
                float4 a0 = ld4f(r0);
                acc[0] = fmaf(p0, a0.x, acc[0]);
                acc[1] = fmaf(p0, a0.y, acc[1]);
                acc[2] = fmaf(p0, a0.z, acc[2]);
                acc[3] = fmaf(p0, a0.w, acc[3]);
            } else if constexpr (V == 2) {
                float2 a0 = ld2f(r0);
                acc[0] = fmaf(p0, a0.x, acc[0]);
                acc[1] = fmaf(p0, a0.y, acc[1]);
            } else {
                acc[0] = fmaf(p0, ldf(r0), acc[0]);
            }
            ssum += p0;
        }
    }

    float inv = 1.f / (ssum + 1e-16f);
    float o[V];
    #pragma unroll
    for (int v = 0; v < V; ++v) {
        o[v] = acc[v] * inv + bias[c0 + v];
        if (DO_ELU) o[v] = (o[v] > 0.f) ? o[v] : expm1f(o[v]);
    }
    // nontemporal stores via plain integer/float types (builtin rejects HIP
    // vector classes); bf16 outputs are packed 2-per-u32.
    if constexpr (sizeof(TOUT) == 2) {
        unsigned int* op = (unsigned int*)(out + (size_t)node * C + c0);
        if constexpr (V == 4) {
            u32x2 w;
            w.x = pack2bf(o[0], o[1]);
            w.y = pack2bf(o[2], o[3]);
            __builtin_nontemporal_store(w, (u32x2*)op);
        } else if constexpr (V == 2) {
            __builtin_nontemporal_store(pack2bf(o[0], o[1]), op);
        } else {
            *(unsigned short*)op = f2bf(o[0]);
        }
    } else {
        float* op = (float*)out + (size_t)node * C + c0;
        #pragma unroll
        for (int v = 0; v < V; ++v) __builtin_nontemporal_store(o[v], op + v);
    }
}

// ---------------------------------------------------------------------------

extern "C" void kernel_launch(void* const* d_in, const int* in_sizes, int n_in,
                              void* d_out, int out_size, void* d_ws, size_t ws_size,
                              hipStream_t stream) {
    const float* x   = (const float*)d_in[0];
    const int*   ei  = (const int*)d_in[1];
    const float* W1  = (const float*)d_in[2];
    const float* as1 = (const float*)d_in[3];
    const float* ad1 = (const float*)d_in[4];
    const float* b1  = (const float*)d_in[5];
    const float* W2  = (const float*)d_in[6];
    const float* as2 = (const float*)d_in[7];
    const float* ad2 = (const float*)d_in[8];
    const float* b2  = (const float*)d_in[9];
    const float* W3  = (const float*)d_in[10];
    const float* as3 = (const float*)d_in[11];
    const float* ad3 = (const float*)d_in[12];
    const float* b3  = (const float*)d_in[13];
    float*       out = (float*)d_out;

    const int N = in_sizes[0] / 256;     // 50000
    const int E = in_sizes[1] / 2;       // 400000

    typedef unsigned short bf;
    size_t off = 0;
    auto alloc = [&](size_t bytes) -> void* {
        void* p = (char*)d_ws + off;
        off += (bytes + 255) & ~(size_t)255;
        return p;
    };
    float* asb    = (float*)alloc((size_t)N * 8 * 4);
    float* adb    = (float*)alloc((size_t)N * 8 * 4);
    int*   deg    = (int*)alloc((size_t)N * 4);
    int*   offs   = (int*)alloc((size_t)(N + 1) * 4);
    int*   cursor = (int*)alloc((size_t)N * 4);
    int*   col    = (int*)alloc((size_t)(E + N) * 4);
    bf*    W1t    = (bf*)alloc((size_t)256 * 1024 * 2);
    bf*    W2t    = (bf*)alloc((size_t)1024 * 512 * 2);
    const size_t NB = (size_t)N * 1024;
    bf* B1 = (bf*)alloc(NB * 2);
    bf* B2 = (bf*)alloc(NB * 2);
    bf* x_bf = B2;   // x_bf (25.6MB) lives in B2's region; dead before agg1 writes B2

    // ---- CSR build ----
    (void)hipMemsetAsync(deg, 0, (size_t)N * 4, stream);
    count_kernel<<<(E + 255) / 256, 256, 0, stream>>>(ei, deg, E, N);
    scan_kernel<<<1, 1024, 0, stream>>>(deg, offs, cursor, N);
    fill_kernel<<<(E + N + 255) / 256, 256, 0, stream>>>(ei, cursor, col, E, N);

    // ---- prep: x -> bf16, W1/W2 -> transposed bf16 ----
    {
        int n4 = N * 256 / 4;
        cvt_bf_kernel<<<(n4 + 255) / 256, 256, 0, stream>>>(x, x_bf, n4);
        transpose_bf_kernel<<<dim3(1024 / 16, 256 / 16), dim3(16, 16), 0, stream>>>(W1, W1t, 256, 1024);
        transpose_bf_kernel<<<dim3(512 / 16, 1024 / 16), dim3(16, 16), 0, stream>>>(W2, W2t, 1024, 512);
    }

    const int MBm = (N + 127) / 128;
    const int AB  = (N + 3) / 4;        // alpha128 blocks (4 nodes/block)

    // ---- layer 1: 256 -> 8 x 128 (MFMA) ----
    gemm_mfma<256, 1024, bf><<<dim3(MBm, 8), 256, 0, stream>>>(x_bf, W1t, B1, N);
    alpha128_kernel<8><<<AB, 256, 0, stream>>>(B1, as1, ad1, asb, adb, N);
    agg_kernel<8, 128, 256, true, bf, bf><<<N, 256, 0, stream>>>(B1, asb, adb, offs, col, b1, B2, N);

    // ---- layer 2: 1024 -> 4 x 128 (MFMA) ----
    gemm_mfma<1024, 512, bf><<<dim3(MBm, 4), 256, 0, stream>>>(B2, W2t, B1, N);
    alpha128_kernel<4><<<AB, 256, 0, stream>>>(B1, as2, ad2, asb, adb, N);
    agg_kernel<4, 128, 256, true, bf, bf><<<N, 256, 0, stream>>>(B1, asb, adb, offs, col, b2, B2, N);

    // ---- layer 3: 512 -> 1 x 64 (fp32 vector, accuracy hedge) ----
    gemm_kernel<512, 64, bf, bf><<<dim3(MBm, 1), 256, 0, stream>>>(B2, W3, B1, N);
    alpha_kernel<1, 64, bf><<<(N + 3) / 4, 256, 0, stream>>>(B1, as3, ad3, asb, adb, N);
    agg_kernel<1, 64, 64, false, bf, float><<<N, 64, 0, stream>>>(B1, asb, adb, offs, col, b3, out, N);
}